// Round 5
// baseline (638.821 us; speedup 1.0000x reference)
//
#include <hip/hip_runtime.h>

// row_attention_maxindex on MI355X — R4:
// (a) flash: fold sum(p) and sum(p*col) into the PV MFMA via a 9th
//     accumulator whose B-columns are synthetic {1, col(k)} fragments —
//     removes 32 of 48 per-iter shuffles (LDS-pipe ds-ops) and all scalar
//     l/aC bookkeeping; alpha-rescale of l/aC comes free (same accumulator).
// (b) merge L/R into single dispatches: 13 -> 6 launches; pO aliased over
//     the y region (ws ~49 MB).

typedef unsigned short u16;
typedef unsigned int   u32;
typedef float        floatx4 __attribute__((ext_vector_type(4)));
typedef unsigned int uintx4  __attribute__((ext_vector_type(4)));
typedef unsigned int uintx2  __attribute__((ext_vector_type(2)));
typedef _Float16     half8   __attribute__((ext_vector_type(8)));

#define HW 4096
#define CB 256
#define RP 128
#define EPSF 1e-5f

static __device__ __forceinline__ u16 f2bf(float f) {
  u32 u = __float_as_uint(f);
  u32 r = u + 0x7FFFu + ((u >> 16) & 1u);   // RNE
  return (u16)(r >> 16);
}
static __device__ __forceinline__ float bf2f(u16 h) {
  return __uint_as_float(((u32)h) << 16);
}
static __device__ __forceinline__ u16 f2h(float f) {
  _Float16 h = (_Float16)f;                 // RNE
  return __builtin_bit_cast(u16, h);
}
static __device__ __forceinline__ float h2f(u16 h) {
  return (float)__builtin_bit_cast(_Float16, h);
}
static __device__ __forceinline__ half8 as_h8(uintx4 v) {
  return __builtin_bit_cast(half8, v);
}

union Pk8 { u16 u[8]; uintx4 v; };
union Pk4 { u16 u[4]; uintx2 v; };

// ---------------------------------------------------------------------------
// Mega-projection: 6 projections in one dispatch. blockIdx>>8 selects config.
// Block: 64 pos x 128 r, 256 threads, thread = 4 pos x 8 r. Output fp16.
// ---------------------------------------------------------------------------
struct ProjCfg {
  const float* x; const float* w; const float* bias;
  const float* add; const float* pre; u16* out;
  int wstride; int transposed;
};
struct ProjCfg6 { ProjCfg c[6]; };

__global__ __launch_bounds__(256) void ra_proj6(ProjCfg6 cfg)
{
  __shared__ float x_lds[32][68];
  __shared__ float w_lds[32][132];
  const ProjCfg C = cfg.c[blockIdx.x >> 8];
  const float* __restrict__ x    = C.x;
  const float* __restrict__ w    = C.w;
  const float* __restrict__ bias = C.bias;
  const float* __restrict__ addend = C.add;
  const float* __restrict__ pre  = C.pre;
  u16* __restrict__ outp = C.out;
  const int wstride = C.wstride;

  const int tid  = threadIdx.x;
  const int inner= blockIdx.x & 255;
  const int b    = inner >> 6;
  const int pos0 = (inner & 63) * 64;
  const int rt = tid & 15, pt = tid >> 4;

  float acc[4][8];
  #pragma unroll
  for (int i = 0; i < 4; i++)
    #pragma unroll
    for (int j = 0; j < 8; j++) acc[i][j] = 0.f;

  const int xc = tid >> 3, xp = (tid & 7) * 8;        // x staging
  const int wr_ = tid >> 1, wc_ = (tid & 1) * 16;     // w staging

  for (int cc = 0; cc < 8; ++cc) {
    {
      const float* xr = x + ((size_t)(b * CB + cc * 32 + xc)) * HW + pos0 + xp;
      floatx4 a0 = *(const floatx4*)xr;
      floatx4 a1 = *(const floatx4*)(xr + 4);
      *(floatx4*)&x_lds[xc][xp]     = a0;
      *(floatx4*)&x_lds[xc][xp + 4] = a1;
    }
    {
      const float* wp = w + (size_t)wr_ * wstride + cc * 32 + wc_;
      #pragma unroll
      for (int jj = 0; jj < 16; jj++) w_lds[wc_ + jj][wr_] = wp[jj];
    }
    __syncthreads();
    #pragma unroll 8
    for (int c = 0; c < 32; c++) {
      floatx4 xv = *(const floatx4*)&x_lds[c][pt * 4];
      floatx4 w0 = *(const floatx4*)&w_lds[c][rt * 8];
      floatx4 w1 = *(const floatx4*)&w_lds[c][rt * 8 + 4];
      #pragma unroll
      for (int i = 0; i < 4; i++) {
        acc[i][0] += xv[i] * w0[0]; acc[i][1] += xv[i] * w0[1];
        acc[i][2] += xv[i] * w0[2]; acc[i][3] += xv[i] * w0[3];
        acc[i][4] += xv[i] * w1[0]; acc[i][5] += xv[i] * w1[1];
        acc[i][6] += xv[i] * w1[2]; acc[i][7] += xv[i] * w1[3];
      }
    }
    __syncthreads();
  }

  if (pre) {  // extra channel 256: pre/128 * w[r][256]
    float wcol[8];
    #pragma unroll
    for (int j = 0; j < 8; j++) wcol[j] = w[(size_t)(rt * 8 + j) * wstride + 256];
    #pragma unroll
    for (int i = 0; i < 4; i++) {
      float pv = pre[(size_t)b * HW + pos0 + pt * 4 + i] * (1.f / 128.f);
      #pragma unroll
      for (int j = 0; j < 8; j++) acc[i][j] += pv * wcol[j];
    }
  }
  #pragma unroll
  for (int j = 0; j < 8; j++) {
    float bs = bias[rt * 8 + j];
    #pragma unroll
    for (int i = 0; i < 4; i++) acc[i][j] += bs;
  }
  if (addend) {  // addend[b][r][pos]
    #pragma unroll
    for (int j = 0; j < 8; j++) {
      floatx4 av = *(const floatx4*)(addend + (size_t)(b * RP + rt * 8 + j) * HW + pos0 + pt * 4);
      #pragma unroll
      for (int i = 0; i < 4; i++) acc[i][j] += av[i];
    }
  }

  if (!C.transposed) {  // out[b][pos][r]
    #pragma unroll
    for (int i = 0; i < 4; i++) {
      Pk8 pk;
      #pragma unroll
      for (int j = 0; j < 8; j++) pk.u[j] = f2h(acc[i][j]);
      *(uintx4*)(outp + (size_t)(b * HW + pos0 + pt * 4 + i) * RP + rt * 8) = pk.v;
    }
  } else {            // out[b][r][pos]
    #pragma unroll
    for (int j = 0; j < 8; j++) {
      Pk4 pk;
      #pragma unroll
      for (int i = 0; i < 4; i++) pk.u[i] = f2h(acc[i][j]);
      *(uintx2*)(outp + (size_t)(b * RP + rt * 8 + j) * HW + pos0 + pt * 4) = pk.v;
    }
  }
}

// ---------------------------------------------------------------------------
// Flash attention partials (both sides, split-K=2). Block: (side, b, 64 q,
// split of 2048 keys), 4 waves x 16 q. 32 K-tiles of 64 keys, double-buffered
// LDS, 1-iter register prefetch. mfma_f32_16x16x32_f16 (layouts m89/m91).
// 9th accumulator = P x [ones | col(k)] folds l and aC into MFMA.
// Emits unnormalized accO (fp16) and m/l/aC (fp32) per query.
// ---------------------------------------------------------------------------
__global__ __launch_bounds__(256) void ra_flash(
    const u16* __restrict__ thetaL, const u16* __restrict__ phiTL,
    const u16* __restrict__ gTL,
    const u16* __restrict__ thetaR, const u16* __restrict__ phiTR,
    const u16* __restrict__ gTR,
    u16* __restrict__ pO, float* __restrict__ mla)
{
  __shared__ uintx4 phi_lds[2][16 * 65];   // [rchunk8 cb(16)][k(64)]
  __shared__ uintx4 g_lds[2][8 * 129];     // [kchunk8 kcb(8)][v(128)]
  __shared__ u16 P_lds[4][16 * 76];        // per-wave [q(16)][k(64)], stride 76

  const int tid  = threadIdx.x;
  const int bx   = blockIdx.x;
  const int side = bx >> 9;
  const int sbx  = bx & 511;
  const u16* __restrict__ theta = side ? thetaR : thetaL;
  const u16* __restrict__ phiT  = side ? phiTR  : phiTL;
  const u16* __restrict__ gT    = side ? gTR    : gTL;

  const int b    = sbx >> 7;
  const int rem  = sbx & 127;
  const int q0   = (rem >> 1) * 64;
  const int split= rem & 1;
  const int kbase= split * 2048;
  const int wv   = tid >> 6;
  const int lane = tid & 63;
  const int ln16 = lane & 15;
  const int quad = lane >> 4;

  // theta A-fragments (held all kernel)
  uintx4 aq[4];
  {
    const uintx4* tr = (const uintx4*)(theta + (size_t)(b * HW + q0 + wv * 16 + ln16) * RP);
    #pragma unroll
    for (int c = 0; c < 4; c++) aq[c] = tr[c * 4 + quad];
  }

  // synthetic B fragments for the l/aC accumulator: col n=0 -> 1.0,
  // n=1 -> col index (par = K-tile parity selects base 0/64), chunk = k/32.
  half8 exf[2][2];
  #pragma unroll
  for (int par = 0; par < 2; par++)
    #pragma unroll
    for (int ch = 0; ch < 2; ch++) {
      const float base = par * 64.f + ch * 32.f + quad * 8.f;
      half8 h;
      #pragma unroll
      for (int jj = 0; jj < 8; jj++) {
        float val = (ln16 == 0) ? 1.0f : (ln16 == 1 ? (base + jj) : 0.0f);
        h[jj] = (_Float16)val;
      }
      exf[par][ch] = h;
    }

  floatx4 accO[9];
  #pragma unroll
  for (int v = 0; v < 9; v++) accO[v] = (floatx4)0.0f;
  float m_r[4];
  #pragma unroll
  for (int r = 0; r < 4; r++) m_r[r] = -3.0e38f;

  const int sk  = tid >> 4, scb = tid & 15;  // phi staging
  const int gv_ = tid >> 3, gcb = tid & 7;   // g staging

  uintx4 sp[4], sg[4];
  #pragma unroll
  for (int i = 0; i < 4; i++) {
    sp[i] = *(const uintx4*)(phiT + (size_t)(b * HW + kbase + i * 16 + sk) * RP + scb * 8);
    sg[i] = *(const uintx4*)(gT + (size_t)(b * RP + i * 32 + gv_) * HW + kbase + gcb * 8);
  }

  #pragma unroll 1
  for (int j = 0; j < 32; j++) {
    const int buf = j & 1;
    #pragma unroll
    for (int i = 0; i < 4; i++) {
      phi_lds[buf][scb * 65 + i * 16 + sk] = sp[i];
      g_lds[buf][gcb * 129 + i * 32 + gv_] = sg[i];
    }
    if (j < 31) {  // prefetch next tile into regs
      const int k0n = kbase + (j + 1) * 64;
      #pragma unroll
      for (int i = 0; i < 4; i++) {
        sp[i] = *(const uintx4*)(phiT + (size_t)(b * HW + k0n + i * 16 + sk) * RP + scb * 8);
        sg[i] = *(const uintx4*)(gT + (size_t)(b * RP + i * 32 + gv_) * HW + k0n + gcb * 8);
      }
    }
    __syncthreads();  // barrier A: tiles visible; orders P read(j-1) vs write(j)

    // S[16q x 64k] = theta . phiT
    floatx4 sf[4];
    #pragma unroll
    for (int s = 0; s < 4; s++) sf[s] = (floatx4)0.0f;
    #pragma unroll
    for (int c = 0; c < 4; c++) {
      half8 a = as_h8(aq[c]);
      #pragma unroll
      for (int s = 0; s < 4; s++) {
        uintx4 bp = phi_lds[buf][(c * 4 + quad) * 65 + s * 16 + ln16];
        sf[s] = __builtin_amdgcn_mfma_f32_16x16x32_f16(a, as_h8(bp), sf[s], 0, 0, 0);
      }
    }

    // online softmax: only the max still needs a cross-lane reduction
    #pragma unroll
    for (int r = 0; r < 4; r++) {
      float mx = fmaxf(fmaxf(sf[0][r], sf[1][r]), fmaxf(sf[2][r], sf[3][r]));
      mx = fmaxf(mx, __shfl_xor(mx, 1));
      mx = fmaxf(mx, __shfl_xor(mx, 2));
      mx = fmaxf(mx, __shfl_xor(mx, 4));
      mx = fmaxf(mx, __shfl_xor(mx, 8));
      const float mnew  = fmaxf(m_r[r], mx);
      const float alpha = __expf(m_r[r] - mnew);
      m_r[r] = mnew;
      const float p0 = __expf(sf[0][r] - mnew);
      const float p1 = __expf(sf[1][r] - mnew);
      const float p2 = __expf(sf[2][r] - mnew);
      const float p3 = __expf(sf[3][r] - mnew);
      #pragma unroll
      for (int v = 0; v < 9; v++) accO[v][r] *= alpha;
      const int qrow = quad * 4 + r;
      P_lds[wv][qrow * 76 +      ln16] = f2h(p0);
      P_lds[wv][qrow * 76 + 16 + ln16] = f2h(p1);
      P_lds[wv][qrow * 76 + 32 + ln16] = f2h(p2);
      P_lds[wv][qrow * 76 + 48 + ln16] = f2h(p3);
    }
    __syncthreads();  // barrier B: P C-layout -> A-layout visible

    half8 pa0 = as_h8(*(const uintx4*)&P_lds[wv][ln16 * 76 + quad * 8]);
    half8 pa1 = as_h8(*(const uintx4*)&P_lds[wv][ln16 * 76 + 32 + quad * 8]);
    #pragma unroll
    for (int v = 0; v < 8; v++) {
      uintx4 bg0 = g_lds[buf][quad * 129 + v * 16 + ln16];
      uintx4 bg1 = g_lds[buf][(4 + quad) * 129 + v * 16 + ln16];
      accO[v] = __builtin_amdgcn_mfma_f32_16x16x32_f16(pa0, as_h8(bg0), accO[v], 0, 0, 0);
      accO[v] = __builtin_amdgcn_mfma_f32_16x16x32_f16(pa1, as_h8(bg1), accO[v], 0, 0, 0);
    }
    const int par = j & 1;
    accO[8] = __builtin_amdgcn_mfma_f32_16x16x32_f16(pa0, exf[par][0], accO[8], 0, 0, 0);
    accO[8] = __builtin_amdgcn_mfma_f32_16x16x32_f16(pa1, exf[par][1], accO[8], 0, 0, 0);
  }

  // epilogue: unnormalized partials. l in col 0, aC in col 1 of accO[8].
  #pragma unroll
  for (int r = 0; r < 4; r++) {
    const int q = q0 + wv * 16 + quad * 4 + r;
    const size_t p = (size_t)side * 32768 + (size_t)split * 16384 + b * HW + q;
    u16* orow = pO + p * RP;
    #pragma unroll
    for (int v = 0; v < 8; v++) orow[v * 16 + ln16] = f2h(accO[v][r]);
    const float v8 = accO[8][r];
    const float lsum = __shfl(v8, quad * 16 + 0);
    const float csum = __shfl(v8, quad * 16 + 1);
    if (ln16 == 0) {
      float* m4 = mla + p * 4;
      m4[0] = m_r[r]; m4[1] = lsum; m4[2] = csum;
    }
  }
}

// ---------------------------------------------------------------------------
// Combine split-K partials (both sides): after (bf16) + index (fp32).
// Block 256 = 2 (side,query) pairs x 128 v. pp in [0, 32768).
// ---------------------------------------------------------------------------
__global__ __launch_bounds__(256) void ra_combine(
    const u16* __restrict__ pO, const float* __restrict__ mla,
    u16* __restrict__ afterL, u16* __restrict__ afterR,
    float* __restrict__ idxL, float* __restrict__ idxR)
{
  const int t = threadIdx.x;
  const int pp = blockIdx.x * 2 + (t >> 7);
  const int side = pp >> 14;
  const int p = pp & 16383;
  const int v = t & 127;
  const size_t base = (size_t)side * 32768;
  const floatx4 A  = *(const floatx4*)(mla + (base + p) * 4);
  const floatx4 Bv = *(const floatx4*)(mla + (base + 16384 + p) * 4);
  const float M  = fmaxf(A[0], Bv[0]);
  const float w0 = __expf(A[0] - M), w1 = __expf(Bv[0] - M);
  const float inv = 1.0f / (w0 * A[1] + w1 * Bv[1]);
  const float a0 = h2f(pO[(base + p) * RP + v]);
  const float a1 = h2f(pO[(base + 16384 + p) * RP + v]);
  u16* after = side ? afterR : afterL;
  after[(size_t)p * RP + v] = f2bf((w0 * a0 + w1 * a1) * inv);
  if (v == 0) {
    float* idx = side ? idxR : idxL;
    idx[p] = (float)(p & 127) - (w0 * A[2] + w1 * Bv[2]) * inv;
  }
}

// ---------------------------------------------------------------------------
// Up-projection (both sides): y[b,co,pos] = after[b,pos,:]·up_w[co,:] + up_b
// ---------------------------------------------------------------------------
__global__ __launch_bounds__(256) void ra_up(
    const u16* __restrict__ afterL, const u16* __restrict__ afterR,
    const float* __restrict__ w, const float* __restrict__ bias,
    u16* __restrict__ yL, u16* __restrict__ yR)
{
  __shared__ float x_lds[32][68];   // [r][pos]
  __shared__ float w_lds[32][132];  // [r][co]
  const int tid  = threadIdx.x;
  const int bx   = blockIdx.x;
  const int side = bx >> 9;
  const int sbx  = bx & 511;
  const u16* __restrict__ after = side ? afterR : afterL;
  u16* __restrict__ y = side ? yR : yL;
  const int b    = sbx >> 7;
  const int pos0 = ((sbx >> 1) & 63) * 64;
  const int hc   = sbx & 1;
  const int rt = tid & 15, pt = tid >> 4;

  float acc[4][8];
  #pragma unroll
  for (int i = 0; i < 4; i++)
    #pragma unroll
    for (int j = 0; j < 8; j++) acc[i][j] = 0.f;

  const int apos = tid >> 2, ars = (tid & 3) * 8;
  const int wr_ = tid >> 1, wc_ = (tid & 1) * 16;

  for (int cc = 0; cc < 4; ++cc) {
    {
      const u16* ar = after + (size_t)(b * HW + pos0 + apos) * RP + cc * 32 + ars;
      uintx4 raw = *(const uintx4*)ar;
      #pragma unroll
      for (int k = 0; k < 4; k++) {
        u32 wd = raw[k];
        x_lds[ars + 2 * k][apos]     = bf2f((u16)(wd & 0xffffu));
        x_lds[ars + 2 * k + 1][apos] = bf2f((u16)(wd >> 16));
      }
    }
    {
      const float* wp = w + (size_t)(hc * 128 + wr_) * RP + cc * 32 + wc_;
      #pragma unroll
      for (int jj = 0; jj < 16; jj++) w_lds[wc_ + jj][wr_] = wp[jj];
    }
    __syncthreads();
    #pragma unroll 8
    for (int c = 0; c < 32; c++) {
      floatx4 xv = *(const floatx4*)&x_lds[c][pt * 4];
      floatx4 w0 = *(const floatx4*)&w_lds[c][rt * 8];
      floatx4 w1 = *(const floatx4*)&w_lds[c][rt * 8 + 4];
      #pragma unroll
      for (int i = 0; i < 4; i++) {
        acc[i][0] += xv[i] * w0[0]; acc[i][1] += xv[i] * w0[1];
        acc[i][2] += xv[i] * w0[2]; acc[i][3] += xv[i] * w0[3];
        acc[i][4] += xv[i] * w1[0]; acc[i][5] += xv[i] * w1[1];
        acc[i][6] += xv[i] * w1[2]; acc[i][7] += xv[i] * w1[3];
      }
    }
    __syncthreads();
  }

  #pragma unroll
  for (int j = 0; j < 8; j++) {
    const int co = hc * 128 + rt * 8 + j;
    const float bs = bias[co];
    Pk4 pk;
    #pragma unroll
    for (int i = 0; i < 4; i++) pk.u[i] = f2bf(acc[i][j] + bs);
    *(uintx2*)(y + (size_t)(b * CB + co) * HW + pos0 + pt * 4) = pk.v;
  }
}

// ---------------------------------------------------------------------------
// Per-channel batch stats (both sides) over (B, HW): mean and rstd.
// ---------------------------------------------------------------------------
__global__ __launch_bounds__(256) void ra_stats(
    const u16* __restrict__ yL, const u16* __restrict__ yR,
    float* __restrict__ stL, float* __restrict__ stR)
{
  const int side = blockIdx.x >> 8;
  const int c = blockIdx.x & 255;
  const u16* __restrict__ y = side ? yR : yL;
  float* __restrict__ stats = side ? stR : stL;
  const int tid = threadIdx.x;
  float s = 0.f, sq = 0.f;
  for (int b = 0; b < 4; b++) {
    const uintx4* row = (const uintx4*)(y + (size_t)(b * CB + c) * HW);
    #pragma unroll
    for (int t = 0; t < 2; t++) {
      uintx4 rv = row[tid + t * 256];
      #pragma unroll
      for (int k = 0; k < 4; k++) {
        float a0 = bf2f((u16)(rv[k] & 0xffffu));
        float a1 = bf2f((u16)(rv[k] >> 16));
        s += a0 + a1; sq += a0 * a0 + a1 * a1;
      }
    }
  }
  #pragma unroll
  for (int m = 1; m < 64; m <<= 1) { s += __shfl_xor(s, m); sq += __shfl_xor(sq, m); }
  __shared__ float red[8];
  const int wv = tid >> 6;
  if ((tid & 63) == 0) { red[wv * 2] = s; red[wv * 2 + 1] = sq; }
  __syncthreads();
  if (tid == 0) {
    s  = red[0] + red[2] + red[4] + red[6];
    sq = red[1] + red[3] + red[5] + red[7];
    const float mean = s * (1.f / 16384.f);
    const float var  = sq * (1.f / 16384.f) - mean * mean;
    stats[2 * c]     = mean;
    stats[2 * c + 1] = rsqrtf(var + EPSF);
  }
}

// ---------------------------------------------------------------------------
// out = x + gamma*(y - mean)*rstd + beta  (both sides, float4)
// ---------------------------------------------------------------------------
__global__ __launch_bounds__(256) void ra_fin(
    const float* __restrict__ left, const float* __restrict__ right,
    const u16* __restrict__ yL, const u16* __restrict__ yR,
    const float* __restrict__ stL, const float* __restrict__ stR,
    const float* __restrict__ gamma, const float* __restrict__ beta,
    float* __restrict__ out)
{
  const size_t e = (size_t)blockIdx.x * 256 + threadIdx.x;  // global float4 idx
  const int side = (int)(e >> 20);
  const size_t e4 = e & 1048575;
  const int c = (int)((e4 >> 10) & 255);
  const float* x = side ? right : left;
  const u16* y = side ? yR : yL;
  const float* stats = side ? stR : stL;
  const float mean = stats[2 * c], rstd = stats[2 * c + 1];
  const float ga = gamma[c], be = beta[c];
  floatx4 xv = ((const floatx4*)x)[e4];
  uintx2 yv = ((const uintx2*)y)[e4];
  float f0 = bf2f((u16)(yv[0] & 0xffffu));
  float f1 = bf2f((u16)(yv[0] >> 16));
  float f2 = bf2f((u16)(yv[1] & 0xffffu));
  float f3 = bf2f((u16)(yv[1] >> 16));
  floatx4 o;
  o[0] = xv[0] + ga * ((f0 - mean) * rstd) + be;
  o[1] = xv[1] + ga * ((f1 - mean) * rstd) + be;
  o[2] = xv[2] + ga * ((f2 - mean) * rstd) + be;
  o[3] = xv[3] + ga * ((f3 - mean) * rstd) + be;
  ((floatx4*)out)[(size_t)side * 1048576 + e4] = o;
}

// ---------------------------------------------------------------------------
extern "C" void kernel_launch(void* const* d_in, const int* in_sizes, int n_in,
                              void* d_out, int out_size, void* d_ws, size_t ws_size,
                              hipStream_t stream)
{
  const float* left    = (const float*)d_in[0];
  const float* right   = (const float*)d_in[1];
  const float* pre_l   = (const float*)d_in[2];
  const float* pre_r   = (const float*)d_in[3];
  const float* query_l = (const float*)d_in[4];
  const float* key_l   = (const float*)d_in[5];
  const float* query_r = (const float*)d_in[6];
  const float* key_r   = (const float*)d_in[7];
  const float* theta_w = (const float*)d_in[8];
  const float* theta_b = (const float*)d_in[9];
  const float* phi_w   = (const float*)d_in[10];
  const float* phi_b   = (const float*)d_in[11];
  const float* g_w     = (const float*)d_in[12];
  const float* g_b     = (const float*)d_in[13];
  const float* up_w    = (const float*)d_in[14];
  const float* up_b    = (const float*)d_in[15];
  const float* bn_g    = (const float*)d_in[16];
  const float* bn_b    = (const float*)d_in[17];
  float* out = (float*)d_out;

  char* ws = (char*)d_ws;
  const size_t SZ = (size_t)4 * HW * RP * 2;  // 4 MiB (fp16 [4][4096][128])
  u16* thetaL = (u16*)(ws);
  u16* phiTL  = (u16*)(ws + 1 * SZ);
  u16* gTL    = (u16*)(ws + 2 * SZ);
  u16* thetaR = (u16*)(ws + 3 * SZ);
  u16* phiTR  = (u16*)(ws + 4 * SZ);
  u16* gTR    = (u16*)(ws + 5 * SZ);
  u16* afterL = (u16*)(ws + 6 * SZ);
  u16* afterR = (u16*)(ws + 7 * SZ);
  u16* pO     = (u16*)(ws + 8 * SZ);    // 16 MiB (2 sides x 2 splits), aliased w/ y
  u16* yL     = (u16*)(ws + 8 * SZ);    // 8 MiB (written after pO is consumed)
  u16* yR     = (u16*)(ws + 10 * SZ);   // 8 MiB
  float* stL  = (float*)(ws + 12 * SZ);
  float* stR  = (float*)(ws + 12 * SZ + 2048);
  float* mla  = (float*)(ws + 12 * SZ + 8192);  // 1 MiB (65536 x 4 fp32)

  dim3 blk(256);
  // side L: x_q=left, x_kv=right, query_l, key_r; side R mirrored.
  ProjCfg6 pc;
  pc.c[0] = { left,  theta_w, theta_b, query_l, pre_l,   thetaL, 257, 0 };
  pc.c[1] = { right, phi_w,   phi_b,   key_r,   nullptr, phiTL,  256, 0 };
  pc.c[2] = { right, g_w,     g_b,     nullptr, nullptr, gTL,    256, 1 };
  pc.c[3] = { right, theta_w, theta_b, query_r, pre_r,   thetaR, 257, 0 };
  pc.c[4] = { left,  phi_w,   phi_b,   key_l,   nullptr, phiTR,  256, 0 };
  pc.c[5] = { left,  g_w,     g_b,     nullptr, nullptr, gTR,    256, 1 };
  ra_proj6<<<1536, blk, 0, stream>>>(pc);

  ra_flash<<<1024, blk, 0, stream>>>(thetaL, phiTL, gTL, thetaR, phiTR, gTR, pO, mla);
  ra_combine<<<16384, blk, 0, stream>>>(pO, mla, afterL, afterR,
                                        out + 8388608, out + 8404992);
  ra_up<<<1024, blk, 0, stream>>>(afterL, afterR, up_w, up_b, yL, yR);
  ra_stats<<<512, blk, 0, stream>>>(yL, yR, stL, stR);
  ra_fin<<<8192, blk, 0, stream>>>(left, right, yL, yR, stL, stR, bn_g, bn_b, out);

  (void)in_sizes; (void)n_in; (void)out_size; (void)ws_size;
}

// Round 6
// 456.661 us; speedup vs baseline: 1.3989x; 1.3989x over previous
//
#include <hip/hip_runtime.h>

// row_attention_maxindex on MI355X — R5: revert R4's 9th-accumulator trick.
// R4 post-mortem: accO[9] + runtime-indexed exf[par][ch] register arrays
// caused per-iteration VALU register-shuffle (VALU-busy 2.24x, flash 230->406
// us). Restore R3's proven 8-acc inner loop (shuffle-reduced ps/pc), KEEP the
// side-merged single flash dispatch + merged combine/up/stats/fin tail.

typedef unsigned short u16;
typedef unsigned int   u32;
typedef float        floatx4 __attribute__((ext_vector_type(4)));
typedef unsigned int uintx4  __attribute__((ext_vector_type(4)));
typedef unsigned int uintx2  __attribute__((ext_vector_type(2)));
typedef _Float16     half8   __attribute__((ext_vector_type(8)));

#define HW 4096
#define CB 256
#define RP 128
#define EPSF 1e-5f

static __device__ __forceinline__ u16 f2bf(float f) {
  u32 u = __float_as_uint(f);
  u32 r = u + 0x7FFFu + ((u >> 16) & 1u);   // RNE
  return (u16)(r >> 16);
}
static __device__ __forceinline__ float bf2f(u16 h) {
  return __uint_as_float(((u32)h) << 16);
}
static __device__ __forceinline__ u16 f2h(float f) {
  _Float16 h = (_Float16)f;                 // RNE
  return __builtin_bit_cast(u16, h);
}
static __device__ __forceinline__ float h2f(u16 h) {
  return (float)__builtin_bit_cast(_Float16, h);
}
static __device__ __forceinline__ half8 as_h8(uintx4 v) {
  return __builtin_bit_cast(half8, v);
}

union Pk8 { u16 u[8]; uintx4 v; };
union Pk4 { u16 u[4]; uintx2 v; };

// ---------------------------------------------------------------------------
// Mega-projection: 6 projections in one dispatch. blockIdx>>8 selects config.
// Block: 64 pos x 128 r, 256 threads, thread = 4 pos x 8 r. Output fp16.
// ---------------------------------------------------------------------------
struct ProjCfg {
  const float* x; const float* w; const float* bias;
  const float* add; const float* pre; u16* out;
  int wstride; int transposed;
};
struct ProjCfg6 { ProjCfg c[6]; };

__global__ __launch_bounds__(256) void ra_proj6(ProjCfg6 cfg)
{
  __shared__ float x_lds[32][68];
  __shared__ float w_lds[32][132];
  const ProjCfg C = cfg.c[blockIdx.x >> 8];
  const float* __restrict__ x    = C.x;
  const float* __restrict__ w    = C.w;
  const float* __restrict__ bias = C.bias;
  const float* __restrict__ addend = C.add;
  const float* __restrict__ pre  = C.pre;
  u16* __restrict__ outp = C.out;
  const int wstride = C.wstride;

  const int tid  = threadIdx.x;
  const int inner= blockIdx.x & 255;
  const int b    = inner >> 6;
  const int pos0 = (inner & 63) * 64;
  const int rt = tid & 15, pt = tid >> 4;

  float acc[4][8];
  #pragma unroll
  for (int i = 0; i < 4; i++)
    #pragma unroll
    for (int j = 0; j < 8; j++) acc[i][j] = 0.f;

  const int xc = tid >> 3, xp = (tid & 7) * 8;        // x staging
  const int wr_ = tid >> 1, wc_ = (tid & 1) * 16;     // w staging

  for (int cc = 0; cc < 8; ++cc) {
    {
      const float* xr = x + ((size_t)(b * CB + cc * 32 + xc)) * HW + pos0 + xp;
      floatx4 a0 = *(const floatx4*)xr;
      floatx4 a1 = *(const floatx4*)(xr + 4);
      *(floatx4*)&x_lds[xc][xp]     = a0;
      *(floatx4*)&x_lds[xc][xp + 4] = a1;
    }
    {
      const float* wp = w + (size_t)wr_ * wstride + cc * 32 + wc_;
      #pragma unroll
      for (int jj = 0; jj < 16; jj++) w_lds[wc_ + jj][wr_] = wp[jj];
    }
    __syncthreads();
    #pragma unroll 8
    for (int c = 0; c < 32; c++) {
      floatx4 xv = *(const floatx4*)&x_lds[c][pt * 4];
      floatx4 w0 = *(const floatx4*)&w_lds[c][rt * 8];
      floatx4 w1 = *(const floatx4*)&w_lds[c][rt * 8 + 4];
      #pragma unroll
      for (int i = 0; i < 4; i++) {
        acc[i][0] += xv[i] * w0[0]; acc[i][1] += xv[i] * w0[1];
        acc[i][2] += xv[i] * w0[2]; acc[i][3] += xv[i] * w0[3];
        acc[i][4] += xv[i] * w1[0]; acc[i][5] += xv[i] * w1[1];
        acc[i][6] += xv[i] * w1[2]; acc[i][7] += xv[i] * w1[3];
      }
    }
    __syncthreads();
  }

  if (pre) {  // extra channel 256: pre/128 * w[r][256]
    float wcol[8];
    #pragma unroll
    for (int j = 0; j < 8; j++) wcol[j] = w[(size_t)(rt * 8 + j) * wstride + 256];
    #pragma unroll
    for (int i = 0; i < 4; i++) {
      float pv = pre[(size_t)b * HW + pos0 + pt * 4 + i] * (1.f / 128.f);
      #pragma unroll
      for (int j = 0; j < 8; j++) acc[i][j] += pv * wcol[j];
    }
  }
  #pragma unroll
  for (int j = 0; j < 8; j++) {
    float bs = bias[rt * 8 + j];
    #pragma unroll
    for (int i = 0; i < 4; i++) acc[i][j] += bs;
  }
  if (addend) {  // addend[b][r][pos]
    #pragma unroll
    for (int j = 0; j < 8; j++) {
      floatx4 av = *(const floatx4*)(addend + (size_t)(b * RP + rt * 8 + j) * HW + pos0 + pt * 4);
      #pragma unroll
      for (int i = 0; i < 4; i++) acc[i][j] += av[i];
    }
  }

  if (!C.transposed) {  // out[b][pos][r]
    #pragma unroll
    for (int i = 0; i < 4; i++) {
      Pk8 pk;
      #pragma unroll
      for (int j = 0; j < 8; j++) pk.u[j] = f2h(acc[i][j]);
      *(uintx4*)(outp + (size_t)(b * HW + pos0 + pt * 4 + i) * RP + rt * 8) = pk.v;
    }
  } else {            // out[b][r][pos]
    #pragma unroll
    for (int j = 0; j < 8; j++) {
      Pk4 pk;
      #pragma unroll
      for (int i = 0; i < 4; i++) pk.u[i] = f2h(acc[i][j]);
      *(uintx2*)(outp + (size_t)(b * RP + rt * 8 + j) * HW + pos0 + pt * 4) = pk.v;
    }
  }
}

// ---------------------------------------------------------------------------
// Flash attention partials (both sides, split-K=2). Block: (side, b, 64 q,
// split of 2048 keys), 4 waves x 16 q. 32 K-tiles of 64 keys, double-buffered
// LDS, 1-iter register prefetch. mfma_f32_16x16x32_f16 (layouts m89/m91).
// R3-proven inner loop: 8 accumulators, shuffle-reduced ps/pc. (R4's 9th-acc
// variant regressed 1.77x: dynamic-indexed register arrays -> VALU shuffle.)
// ---------------------------------------------------------------------------
__global__ __launch_bounds__(256) void ra_flash(
    const u16* __restrict__ thetaL, const u16* __restrict__ phiTL,
    const u16* __restrict__ gTL,
    const u16* __restrict__ thetaR, const u16* __restrict__ phiTR,
    const u16* __restrict__ gTR,
    u16* __restrict__ pO, float* __restrict__ mla)
{
  __shared__ uintx4 phi_lds[2][16 * 65];   // [rchunk8 cb(16)][k(64)]
  __shared__ uintx4 g_lds[2][8 * 129];     // [kchunk8 kcb(8)][v(128)]
  __shared__ u16 P_lds[4][16 * 76];        // per-wave [q(16)][k(64)], stride 76

  const int tid  = threadIdx.x;
  const int bx   = blockIdx.x;
  const int side = bx >> 9;
  const int sbx  = bx & 511;
  const u16* __restrict__ theta = side ? thetaR : thetaL;
  const u16* __restrict__ phiT  = side ? phiTR  : phiTL;
  const u16* __restrict__ gT    = side ? gTR    : gTL;

  const int b    = sbx >> 7;
  const int rem  = sbx & 127;
  const int q0   = (rem >> 1) * 64;
  const int split= rem & 1;
  const int kbase= split * 2048;
  const int wv   = tid >> 6;
  const int lane = tid & 63;
  const int ln16 = lane & 15;
  const int quad = lane >> 4;

  // theta A-fragments (held all kernel)
  uintx4 aq[4];
  {
    const uintx4* tr = (const uintx4*)(theta + (size_t)(b * HW + q0 + wv * 16 + ln16) * RP);
    #pragma unroll
    for (int c = 0; c < 4; c++) aq[c] = tr[c * 4 + quad];
  }

  floatx4 accO[8];
  #pragma unroll
  for (int v = 0; v < 8; v++) accO[v] = (floatx4)0.0f;
  float m_r[4], l_r[4], aC[4];
  #pragma unroll
  for (int r = 0; r < 4; r++) { m_r[r] = -3.0e38f; l_r[r] = 0.f; aC[r] = 0.f; }

  const int sk  = tid >> 4, scb = tid & 15;  // phi staging
  const int gv_ = tid >> 3, gcb = tid & 7;   // g staging

  uintx4 sp[4], sg[4];
  #pragma unroll
  for (int i = 0; i < 4; i++) {
    sp[i] = *(const uintx4*)(phiT + (size_t)(b * HW + kbase + i * 16 + sk) * RP + scb * 8);
    sg[i] = *(const uintx4*)(gT + (size_t)(b * RP + i * 32 + gv_) * HW + kbase + gcb * 8);
  }

  #pragma unroll 1
  for (int j = 0; j < 32; j++) {
    const int buf = j & 1;
    #pragma unroll
    for (int i = 0; i < 4; i++) {
      phi_lds[buf][scb * 65 + i * 16 + sk] = sp[i];
      g_lds[buf][gcb * 129 + i * 32 + gv_] = sg[i];
    }
    if (j < 31) {  // prefetch next tile into regs
      const int k0n = kbase + (j + 1) * 64;
      #pragma unroll
      for (int i = 0; i < 4; i++) {
        sp[i] = *(const uintx4*)(phiT + (size_t)(b * HW + k0n + i * 16 + sk) * RP + scb * 8);
        sg[i] = *(const uintx4*)(gT + (size_t)(b * RP + i * 32 + gv_) * HW + k0n + gcb * 8);
      }
    }
    __syncthreads();  // barrier A: tiles visible; orders P read(j-1) vs write(j)

    // S[16q x 64k] = theta . phiT
    floatx4 sf[4];
    #pragma unroll
    for (int s = 0; s < 4; s++) sf[s] = (floatx4)0.0f;
    #pragma unroll
    for (int c = 0; c < 4; c++) {
      half8 a = as_h8(aq[c]);
      #pragma unroll
      for (int s = 0; s < 4; s++) {
        uintx4 bp = phi_lds[buf][(c * 4 + quad) * 65 + s * 16 + ln16];
        sf[s] = __builtin_amdgcn_mfma_f32_16x16x32_f16(a, as_h8(bp), sf[s], 0, 0, 0);
      }
    }

    // online softmax + col accumulation; write P (fp16) for A-operand re-read
    const float colbase = (float)((j * 64) & 127) + (float)ln16;  // kbase%128==0
    #pragma unroll
    for (int r = 0; r < 4; r++) {
      float mx = fmaxf(fmaxf(sf[0][r], sf[1][r]), fmaxf(sf[2][r], sf[3][r]));
      mx = fmaxf(mx, __shfl_xor(mx, 1));
      mx = fmaxf(mx, __shfl_xor(mx, 2));
      mx = fmaxf(mx, __shfl_xor(mx, 4));
      mx = fmaxf(mx, __shfl_xor(mx, 8));
      const float mnew  = fmaxf(m_r[r], mx);
      const float alpha = __expf(m_r[r] - mnew);
      m_r[r] = mnew;
      float p0 = __expf(sf[0][r] - mnew);
      float p1 = __expf(sf[1][r] - mnew);
      float p2 = __expf(sf[2][r] - mnew);
      float p3 = __expf(sf[3][r] - mnew);
      float ps = p0 + p1 + p2 + p3;
      float pc = p0 * colbase + p1 * (colbase + 16.f) + p2 * (colbase + 32.f) + p3 * (colbase + 48.f);
      ps += __shfl_xor(ps, 1); ps += __shfl_xor(ps, 2);
      ps += __shfl_xor(ps, 4); ps += __shfl_xor(ps, 8);
      pc += __shfl_xor(pc, 1); pc += __shfl_xor(pc, 2);
      pc += __shfl_xor(pc, 4); pc += __shfl_xor(pc, 8);
      l_r[r] = l_r[r] * alpha + ps;
      aC[r]  = aC[r]  * alpha + pc;
      #pragma unroll
      for (int v = 0; v < 8; v++) accO[v][r] *= alpha;
      const int qrow = quad * 4 + r;
      P_lds[wv][qrow * 76 +      ln16] = f2h(p0);
      P_lds[wv][qrow * 76 + 16 + ln16] = f2h(p1);
      P_lds[wv][qrow * 76 + 32 + ln16] = f2h(p2);
      P_lds[wv][qrow * 76 + 48 + ln16] = f2h(p3);
    }
    __syncthreads();  // barrier B: P C-layout -> A-layout visible

    half8 pa0 = as_h8(*(const uintx4*)&P_lds[wv][ln16 * 76 + quad * 8]);
    half8 pa1 = as_h8(*(const uintx4*)&P_lds[wv][ln16 * 76 + 32 + quad * 8]);
    #pragma unroll
    for (int v = 0; v < 8; v++) {
      uintx4 bg0 = g_lds[buf][quad * 129 + v * 16 + ln16];
      uintx4 bg1 = g_lds[buf][(4 + quad) * 129 + v * 16 + ln16];
      accO[v] = __builtin_amdgcn_mfma_f32_16x16x32_f16(pa0, as_h8(bg0), accO[v], 0, 0, 0);
      accO[v] = __builtin_amdgcn_mfma_f32_16x16x32_f16(pa1, as_h8(bg1), accO[v], 0, 0, 0);
    }
  }

  // epilogue: unnormalized partials
  #pragma unroll
  for (int r = 0; r < 4; r++) {
    const int q = q0 + wv * 16 + quad * 4 + r;
    const size_t p = (size_t)side * 32768 + (size_t)split * 16384 + b * HW + q;
    u16* orow = pO + p * RP;
    #pragma unroll
    for (int v = 0; v < 8; v++) orow[v * 16 + ln16] = f2h(accO[v][r]);
    if (ln16 == 0) {
      float* m4 = mla + p * 4;
      m4[0] = m_r[r]; m4[1] = l_r[r]; m4[2] = aC[r];
    }
  }
}

// ---------------------------------------------------------------------------
// Combine split-K partials (both sides): after (bf16) + index (fp32).
// Block 256 = 2 (side,query) pairs x 128 v. pp in [0, 32768).
// ---------------------------------------------------------------------------
__global__ __launch_bounds__(256) void ra_combine(
    const u16* __restrict__ pO, const float* __restrict__ mla,
    u16* __restrict__ afterL, u16* __restrict__ afterR,
    float* __restrict__ idxL, float* __restrict__ idxR)
{
  const int t = threadIdx.x;
  const int pp = blockIdx.x * 2 + (t >> 7);
  const int side = pp >> 14;
  const int p = pp & 16383;
  const int v = t & 127;
  const size_t base = (size_t)side * 32768;
  const floatx4 A  = *(const floatx4*)(mla + (base + p) * 4);
  const floatx4 Bv = *(const floatx4*)(mla + (base + 16384 + p) * 4);
  const float M  = fmaxf(A[0], Bv[0]);
  const float w0 = __expf(A[0] - M), w1 = __expf(Bv[0] - M);
  const float inv = 1.0f / (w0 * A[1] + w1 * Bv[1]);
  const float a0 = h2f(pO[(base + p) * RP + v]);
  const float a1 = h2f(pO[(base + 16384 + p) * RP + v]);
  u16* after = side ? afterR : afterL;
  after[(size_t)p * RP + v] = f2bf((w0 * a0 + w1 * a1) * inv);
  if (v == 0) {
    float* idx = side ? idxR : idxL;
    idx[p] = (float)(p & 127) - (w0 * A[2] + w1 * Bv[2]) * inv;
  }
}

// ---------------------------------------------------------------------------
// Up-projection (both sides): y[b,co,pos] = after[b,pos,:]·up_w[co,:] + up_b
// ---------------------------------------------------------------------------
__global__ __launch_bounds__(256) void ra_up(
    const u16* __restrict__ afterL, const u16* __restrict__ afterR,
    const float* __restrict__ w, const float* __restrict__ bias,
    u16* __restrict__ yL, u16* __restrict__ yR)
{
  __shared__ float x_lds[32][68];   // [r][pos]
  __shared__ float w_lds[32][132];  // [r][co]
  const int tid  = threadIdx.x;
  const int bx   = blockIdx.x;
  const int side = bx >> 9;
  const int sbx  = bx & 511;
  const u16* __restrict__ after = side ? afterR : afterL;
  u16* __restrict__ y = side ? yR : yL;
  const int b    = sbx >> 7;
  const int pos0 = ((sbx >> 1) & 63) * 64;
  const int hc   = sbx & 1;
  const int rt = tid & 15, pt = tid >> 4;

  float acc[4][8];
  #pragma unroll
  for (int i = 0; i < 4; i++)
    #pragma unroll
    for (int j = 0; j < 8; j++) acc[i][j] = 0.f;

  const int apos = tid >> 2, ars = (tid & 3) * 8;
  const int wr_ = tid >> 1, wc_ = (tid & 1) * 16;

  for (int cc = 0; cc < 4; ++cc) {
    {
      const u16* ar = after + (size_t)(b * HW + pos0 + apos) * RP + cc * 32 + ars;
      uintx4 raw = *(const uintx4*)ar;
      #pragma unroll
      for (int k = 0; k < 4; k++) {
        u32 wd = raw[k];
        x_lds[ars + 2 * k][apos]     = bf2f((u16)(wd & 0xffffu));
        x_lds[ars + 2 * k + 1][apos] = bf2f((u16)(wd >> 16));
      }
    }
    {
      const float* wp = w + (size_t)(hc * 128 + wr_) * RP + cc * 32 + wc_;
      #pragma unroll
      for (int jj = 0; jj < 16; jj++) w_lds[wc_ + jj][wr_] = wp[jj];
    }
    __syncthreads();
    #pragma unroll 8
    for (int c = 0; c < 32; c++) {
      floatx4 xv = *(const floatx4*)&x_lds[c][pt * 4];
      floatx4 w0 = *(const floatx4*)&w_lds[c][rt * 8];
      floatx4 w1 = *(const floatx4*)&w_lds[c][rt * 8 + 4];
      #pragma unroll
      for (int i = 0; i < 4; i++) {
        acc[i][0] += xv[i] * w0[0]; acc[i][1] += xv[i] * w0[1];
        acc[i][2] += xv[i] * w0[2]; acc[i][3] += xv[i] * w0[3];
        acc[i][4] += xv[i] * w1[0]; acc[i][5] += xv[i] * w1[1];
        acc[i][6] += xv[i] * w1[2]; acc[i][7] += xv[i] * w1[3];
      }
    }
    __syncthreads();
  }

  #pragma unroll
  for (int j = 0; j < 8; j++) {
    const int co = hc * 128 + rt * 8 + j;
    const float bs = bias[co];
    Pk4 pk;
    #pragma unroll
    for (int i = 0; i < 4; i++) pk.u[i] = f2bf(acc[i][j] + bs);
    *(uintx2*)(y + (size_t)(b * CB + co) * HW + pos0 + pt * 4) = pk.v;
  }
}

// ---------------------------------------------------------------------------
// Per-channel batch stats (both sides) over (B, HW): mean and rstd.
// ---------------------------------------------------------------------------
__global__ __launch_bounds__(256) void ra_stats(
    const u16* __restrict__ yL, const u16* __restrict__ yR,
    float* __restrict__ stL, float* __restrict__ stR)
{
  const int side = blockIdx.x >> 8;
  const int c = blockIdx.x & 255;
  const u16* __restrict__ y = side ? yR : yL;
  float* __restrict__ stats = side ? stR : stL;
  const int tid = threadIdx.x;
  float s = 0.f, sq = 0.f;
  for (int b = 0; b < 4; b++) {
    const uintx4* row = (const uintx4*)(y + (size_t)(b * CB + c) * HW);
    #pragma unroll
    for (int t = 0; t < 2; t++) {
      uintx4 rv = row[tid + t * 256];
      #pragma unroll
      for (int k = 0; k < 4; k++) {
        float a0 = bf2f((u16)(rv[k] & 0xffffu));
        float a1 = bf2f((u16)(rv[k] >> 16));
        s += a0 + a1; sq += a0 * a0 + a1 * a1;
      }
    }
  }
  #pragma unroll
  for (int m = 1; m < 64; m <<= 1) { s += __shfl_xor(s, m); sq += __shfl_xor(sq, m); }
  __shared__ float red[8];
  const int wv = tid >> 6;
  if ((tid & 63) == 0) { red[wv * 2] = s; red[wv * 2 + 1] = sq; }
  __syncthreads();
  if (tid == 0) {
    s  = red[0] + red[2] + red[4] + red[6];
    sq = red[1] + red[3] + red[5] + red[7];
    const float mean = s * (1.f / 16384.f);
    const float var  = sq * (1.f / 16384.f) - mean * mean;
    stats[2 * c]     = mean;
    stats[2 * c + 1] = rsqrtf(var + EPSF);
  }
}

// ---------------------------------------------------------------------------
// out = x + gamma*(y - mean)*rstd + beta  (both sides, float4)
// ---------------------------------------------------------------------------
__global__ __launch_bounds__(256) void ra_fin(
    const float* __restrict__ left, const float* __restrict__ right,
    const u16* __restrict__ yL, const u16* __restrict__ yR,
    const float* __restrict__ stL, const float* __restrict__ stR,
    const float* __restrict__ gamma, const float* __restrict__ beta,
    float* __restrict__ out)
{
  const size_t e = (size_t)blockIdx.x * 256 + threadIdx.x;  // global float4 idx
  const int side = (int)(e >> 20);
  const size_t e4 = e & 1048575;
  const int c = (int)((e4 >> 10) & 255);
  const float* x = side ? right : left;
  const u16* y = side ? yR : yL;
  const float* stats = side ? stR : stL;
  const float mean = stats[2 * c], rstd = stats[2 * c + 1];
  const float ga = gamma[c], be = beta[c];
  floatx4 xv = ((const floatx4*)x)[e4];
  uintx2 yv = ((const uintx2*)y)[e4];
  float f0 = bf2f((u16)(yv[0] & 0xffffu));
  float f1 = bf2f((u16)(yv[0] >> 16));
  float f2 = bf2f((u16)(yv[1] & 0xffffu));
  float f3 = bf2f((u16)(yv[1] >> 16));
  floatx4 o;
  o[0] = xv[0] + ga * ((f0 - mean) * rstd) + be;
  o[1] = xv[1] + ga * ((f1 - mean) * rstd) + be;
  o[2] = xv[2] + ga * ((f2 - mean) * rstd) + be;
  o[3] = xv[3] + ga * ((f3 - mean) * rstd) + be;
  ((floatx4*)out)[(size_t)side * 1048576 + e4] = o;
}

// ---------------------------------------------------------------------------
extern "C" void kernel_launch(void* const* d_in, const int* in_sizes, int n_in,
                              void* d_out, int out_size, void* d_ws, size_t ws_size,
                              hipStream_t stream)
{
  const float* left    = (const float*)d_in[0];
  const float* right   = (const float*)d_in[1];
  const float* pre_l   = (const float*)d_in[2];
  const float* pre_r   = (const float*)d_in[3];
  const float* query_l = (const float*)d_in[4];
  const float* key_l   = (const float*)d_in[5];
  const float* query_r = (const float*)d_in[6];
  const float* key_r   = (const float*)d_in[7];
  const float* theta_w = (const float*)d_in[8];
  const float* theta_b = (const float*)d_in[9];
  const float* phi_w   = (const float*)d_in[10];
  const float* phi_b   = (const float*)d_in[11];
  const float* g_w     = (const float*)d_in[12];
  const float* g_b     = (const float*)d_in[13];
  const float* up_w    = (const float*)d_in[14];
  const float* up_b    = (const float*)d_in[15];
  const float* bn_g    = (const float*)d_in[16];
  const float* bn_b    = (const float*)d_in[17];
  float* out = (float*)d_out;

  char* ws = (char*)d_ws;
  const size_t SZ = (size_t)4 * HW * RP * 2;  // 4 MiB (fp16 [4][4096][128])
  u16* thetaL = (u16*)(ws);
  u16* phiTL  = (u16*)(ws + 1 * SZ);
  u16* gTL    = (u16*)(ws + 2 * SZ);
  u16* thetaR = (u16*)(ws + 3 * SZ);
  u16* phiTR  = (u16*)(ws + 4 * SZ);
  u16* gTR    = (u16*)(ws + 5 * SZ);
  u16* afterL = (u16*)(ws + 6 * SZ);
  u16* afterR = (u16*)(ws + 7 * SZ);
  u16* pO     = (u16*)(ws + 8 * SZ);    // 16 MiB (2 sides x 2 splits), aliased w/ y
  u16* yL     = (u16*)(ws + 8 * SZ);    // 8 MiB (written after pO is consumed)
  u16* yR     = (u16*)(ws + 10 * SZ);   // 8 MiB
  float* stL  = (float*)(ws + 12 * SZ);
  float* stR  = (float*)(ws + 12 * SZ + 2048);
  float* mla  = (float*)(ws + 12 * SZ + 8192);  // 1 MiB (65536 x 4 fp32)

  dim3 blk(256);
  // side L: x_q=left, x_kv=right, query_l, key_r; side R mirrored.
  ProjCfg6 pc;
  pc.c[0] = { left,  theta_w, theta_b, query_l, pre_l,   thetaL, 257, 0 };
  pc.c[1] = { right, phi_w,   phi_b,   key_r,   nullptr, phiTL,  256, 0 };
  pc.c[2] = { right, g_w,     g_b,     nullptr, nullptr, gTL,    256, 1 };
  pc.c[3] = { right, theta_w, theta_b, query_r, pre_r,   thetaR, 257, 0 };
  pc.c[4] = { left,  phi_w,   phi_b,   key_l,   nullptr, phiTR,  256, 0 };
  pc.c[5] = { left,  g_w,     g_b,     nullptr, nullptr, gTR,    256, 1 };
  ra_proj6<<<1536, blk, 0, stream>>>(pc);

  ra_flash<<<1024, blk, 0, stream>>>(thetaL, phiTL, gTL, thetaR, phiTR, gTR, pO, mla);
  ra_combine<<<16384, blk, 0, stream>>>(pO, mla, afterL, afterR,
                                        out + 8388608, out + 8404992);
  ra_up<<<1024, blk, 0, stream>>>(afterL, afterR, up_w, up_b, yL, yR);
  ra_stats<<<512, blk, 0, stream>>>(yL, yR, stL, stR);
  ra_fin<<<8192, blk, 0, stream>>>(left, right, yL, yR, stL, stR, bn_g, bn_b, out);

  (void)in_sizes; (void)n_in; (void)out_size; (void)ws_size;
}

// Round 7
// 403.146 us; speedup vs baseline: 1.5846x; 1.1327x over previous
//
#include <hip/hip_runtime.h>

// row_attention_maxindex on MI355X — R6: transposed-S flash.
// S^T = phi·theta^T puts queries in lane columns: softmax is per-lane over 16
// register values -> 48 shuffles/iter -> 6; P written as 4x ds_write_b64;
// barrier B removed (P_lds is wave-private; intra-wave DS ordering suffices);
// epilogue 8x b64 stores. All LDS fragment reads identical to R5 (A/B operand
// lane addressing is the same map) — only MFMA operand order swaps.

typedef unsigned short u16;
typedef unsigned int   u32;
typedef float        floatx4 __attribute__((ext_vector_type(4)));
typedef unsigned int uintx4  __attribute__((ext_vector_type(4)));
typedef unsigned int uintx2  __attribute__((ext_vector_type(2)));
typedef _Float16     half8   __attribute__((ext_vector_type(8)));

#define HW 4096
#define CB 256
#define RP 128
#define EPSF 1e-5f

static __device__ __forceinline__ u16 f2bf(float f) {
  u32 u = __float_as_uint(f);
  u32 r = u + 0x7FFFu + ((u >> 16) & 1u);   // RNE
  return (u16)(r >> 16);
}
static __device__ __forceinline__ float bf2f(u16 h) {
  return __uint_as_float(((u32)h) << 16);
}
static __device__ __forceinline__ u16 f2h(float f) {
  _Float16 h = (_Float16)f;                 // RNE
  return __builtin_bit_cast(u16, h);
}
static __device__ __forceinline__ float h2f(u16 h) {
  return (float)__builtin_bit_cast(_Float16, h);
}
static __device__ __forceinline__ half8 as_h8(uintx4 v) {
  return __builtin_bit_cast(half8, v);
}

union Pk8 { u16 u[8]; uintx4 v; };
union Pk4 { u16 u[4]; uintx2 v; };

// ---------------------------------------------------------------------------
// Mega-projection: 6 projections in one dispatch. blockIdx>>8 selects config.
// Block: 64 pos x 128 r, 256 threads, thread = 4 pos x 8 r. Output fp16.
// ---------------------------------------------------------------------------
struct ProjCfg {
  const float* x; const float* w; const float* bias;
  const float* add; const float* pre; u16* out;
  int wstride; int transposed;
};
struct ProjCfg6 { ProjCfg c[6]; };

__global__ __launch_bounds__(256) void ra_proj6(ProjCfg6 cfg)
{
  __shared__ float x_lds[32][68];
  __shared__ float w_lds[32][132];
  const ProjCfg C = cfg.c[blockIdx.x >> 8];
  const float* __restrict__ x    = C.x;
  const float* __restrict__ w    = C.w;
  const float* __restrict__ bias = C.bias;
  const float* __restrict__ addend = C.add;
  const float* __restrict__ pre  = C.pre;
  u16* __restrict__ outp = C.out;
  const int wstride = C.wstride;

  const int tid  = threadIdx.x;
  const int inner= blockIdx.x & 255;
  const int b    = inner >> 6;
  const int pos0 = (inner & 63) * 64;
  const int rt = tid & 15, pt = tid >> 4;

  float acc[4][8];
  #pragma unroll
  for (int i = 0; i < 4; i++)
    #pragma unroll
    for (int j = 0; j < 8; j++) acc[i][j] = 0.f;

  const int xc = tid >> 3, xp = (tid & 7) * 8;        // x staging
  const int wr_ = tid >> 1, wc_ = (tid & 1) * 16;     // w staging

  for (int cc = 0; cc < 8; ++cc) {
    {
      const float* xr = x + ((size_t)(b * CB + cc * 32 + xc)) * HW + pos0 + xp;
      floatx4 a0 = *(const floatx4*)xr;
      floatx4 a1 = *(const floatx4*)(xr + 4);
      *(floatx4*)&x_lds[xc][xp]     = a0;
      *(floatx4*)&x_lds[xc][xp + 4] = a1;
    }
    {
      const float* wp = w + (size_t)wr_ * wstride + cc * 32 + wc_;
      #pragma unroll
      for (int jj = 0; jj < 16; jj++) w_lds[wc_ + jj][wr_] = wp[jj];
    }
    __syncthreads();
    #pragma unroll 8
    for (int c = 0; c < 32; c++) {
      floatx4 xv = *(const floatx4*)&x_lds[c][pt * 4];
      floatx4 w0 = *(const floatx4*)&w_lds[c][rt * 8];
      floatx4 w1 = *(const floatx4*)&w_lds[c][rt * 8 + 4];
      #pragma unroll
      for (int i = 0; i < 4; i++) {
        acc[i][0] += xv[i] * w0[0]; acc[i][1] += xv[i] * w0[1];
        acc[i][2] += xv[i] * w0[2]; acc[i][3] += xv[i] * w0[3];
        acc[i][4] += xv[i] * w1[0]; acc[i][5] += xv[i] * w1[1];
        acc[i][6] += xv[i] * w1[2]; acc[i][7] += xv[i] * w1[3];
      }
    }
    __syncthreads();
  }

  if (pre) {  // extra channel 256: pre/128 * w[r][256]
    float wcol[8];
    #pragma unroll
    for (int j = 0; j < 8; j++) wcol[j] = w[(size_t)(rt * 8 + j) * wstride + 256];
    #pragma unroll
    for (int i = 0; i < 4; i++) {
      float pv = pre[(size_t)b * HW + pos0 + pt * 4 + i] * (1.f / 128.f);
      #pragma unroll
      for (int j = 0; j < 8; j++) acc[i][j] += pv * wcol[j];
    }
  }
  #pragma unroll
  for (int j = 0; j < 8; j++) {
    float bs = bias[rt * 8 + j];
    #pragma unroll
    for (int i = 0; i < 4; i++) acc[i][j] += bs;
  }
  if (addend) {  // addend[b][r][pos]
    #pragma unroll
    for (int j = 0; j < 8; j++) {
      floatx4 av = *(const floatx4*)(addend + (size_t)(b * RP + rt * 8 + j) * HW + pos0 + pt * 4);
      #pragma unroll
      for (int i = 0; i < 4; i++) acc[i][j] += av[i];
    }
  }

  if (!C.transposed) {  // out[b][pos][r]
    #pragma unroll
    for (int i = 0; i < 4; i++) {
      Pk8 pk;
      #pragma unroll
      for (int j = 0; j < 8; j++) pk.u[j] = f2h(acc[i][j]);
      *(uintx4*)(outp + (size_t)(b * HW + pos0 + pt * 4 + i) * RP + rt * 8) = pk.v;
    }
  } else {            // out[b][r][pos]
    #pragma unroll
    for (int j = 0; j < 8; j++) {
      Pk4 pk;
      #pragma unroll
      for (int i = 0; i < 4; i++) pk.u[i] = f2h(acc[i][j]);
      *(uintx2*)(outp + (size_t)(b * RP + rt * 8 + j) * HW + pos0 + pt * 4) = pk.v;
    }
  }
}

// ---------------------------------------------------------------------------
// Flash attention partials (both sides, split-K=2), transposed-S form.
// Block: (side, b, 64 q, split of 2048 keys), 4 waves x 16 q. 32 K-tiles of
// 64 keys, double-buffered LDS, 1-iter register prefetch, ONE barrier/iter.
// S^T[key][q] = mfma(A=phi, B=theta): D[row=quad*4+r = key][col=ln16 = q].
// after^T[v][q] = mfma(A=g, B=P): per-lane v=quad*4+r (x8 tiles), q=ln16.
// Softmax per-lane (query=ln16) over 16 local values; 6 shuffles/iter.
// ---------------------------------------------------------------------------
__global__ __launch_bounds__(256) void ra_flash(
    const u16* __restrict__ thetaL, const u16* __restrict__ phiTL,
    const u16* __restrict__ gTL,
    const u16* __restrict__ thetaR, const u16* __restrict__ phiTR,
    const u16* __restrict__ gTR,
    u16* __restrict__ pO, float* __restrict__ mla)
{
  __shared__ uintx4 phi_lds[2][16 * 65];   // [rchunk8 cb(16)][k(64)]
  __shared__ uintx4 g_lds[2][8 * 129];     // [kchunk8 kcb(8)][v(128)]
  __shared__ u16 P_lds[4][16 * 76];        // per-wave [q(16)][k(64)], stride 76

  const int tid  = threadIdx.x;
  const int bx   = blockIdx.x;
  const int side = bx >> 9;
  const int sbx  = bx & 511;
  const u16* __restrict__ theta = side ? thetaR : thetaL;
  const u16* __restrict__ phiT  = side ? phiTR  : phiTL;
  const u16* __restrict__ gT    = side ? gTR    : gTL;

  const int b    = sbx >> 7;
  const int rem  = sbx & 127;
  const int q0   = (rem >> 1) * 64;
  const int split= rem & 1;
  const int kbase= split * 2048;
  const int wv   = tid >> 6;
  const int lane = tid & 63;
  const int ln16 = lane & 15;
  const int quad = lane >> 4;

  // theta fragments (held all kernel); used as B-operand: B[k=r][n=q=ln16]
  uintx4 aq[4];
  {
    const uintx4* tr = (const uintx4*)(theta + (size_t)(b * HW + q0 + wv * 16 + ln16) * RP);
    #pragma unroll
    for (int c = 0; c < 4; c++) aq[c] = tr[c * 4 + quad];
  }

  floatx4 accO[8];   // accO[vt][r] = after^T[v=vt*16+quad*4+r][q=ln16]
  #pragma unroll
  for (int v = 0; v < 8; v++) accO[v] = (floatx4)0.0f;
  float m_q = -3.0e38f, l_q = 0.f, aC_q = 0.f;   // per-lane query state

  const int sk  = tid >> 4, scb = tid & 15;  // phi staging
  const int gv_ = tid >> 3, gcb = tid & 7;   // g staging

  uintx4 sp[4], sg[4];
  #pragma unroll
  for (int i = 0; i < 4; i++) {
    sp[i] = *(const uintx4*)(phiT + (size_t)(b * HW + kbase + i * 16 + sk) * RP + scb * 8);
    sg[i] = *(const uintx4*)(gT + (size_t)(b * RP + i * 32 + gv_) * HW + kbase + gcb * 8);
  }

  #pragma unroll 1
  for (int j = 0; j < 32; j++) {
    const int buf = j & 1;
    #pragma unroll
    for (int i = 0; i < 4; i++) {
      phi_lds[buf][scb * 65 + i * 16 + sk] = sp[i];
      g_lds[buf][gcb * 129 + i * 32 + gv_] = sg[i];
    }
    if (j < 31) {  // prefetch next tile into regs
      const int k0n = kbase + (j + 1) * 64;
      #pragma unroll
      for (int i = 0; i < 4; i++) {
        sp[i] = *(const uintx4*)(phiT + (size_t)(b * HW + k0n + i * 16 + sk) * RP + scb * 8);
        sg[i] = *(const uintx4*)(gT + (size_t)(b * RP + i * 32 + gv_) * HW + k0n + gcb * 8);
      }
    }
    __syncthreads();  // single barrier: tiles visible; dbuf protects reuse

    // S^T[64k x 16q] = phi . theta^T   (sf[s][r]: key=s*16+quad*4+r, q=ln16)
    floatx4 sf[4];
    #pragma unroll
    for (int s = 0; s < 4; s++) sf[s] = (floatx4)0.0f;
    #pragma unroll
    for (int c = 0; c < 4; c++) {
      half8 bth = as_h8(aq[c]);
      #pragma unroll
      for (int s = 0; s < 4; s++) {
        uintx4 ap = phi_lds[buf][(c * 4 + quad) * 65 + s * 16 + ln16];
        sf[s] = __builtin_amdgcn_mfma_f32_16x16x32_f16(as_h8(ap), bth, sf[s], 0, 0, 0);
      }
    }

    // per-lane online softmax for query ln16 (16 local values, 6 shuffles)
    float mx = sf[0][0];
    #pragma unroll
    for (int s = 0; s < 4; s++)
      #pragma unroll
      for (int r = 0; r < 4; r++) mx = fmaxf(mx, sf[s][r]);
    mx = fmaxf(mx, __shfl_xor(mx, 16));
    mx = fmaxf(mx, __shfl_xor(mx, 32));
    const float mnew  = fmaxf(m_q, mx);
    const float alpha = __expf(m_q - mnew);
    m_q = mnew;
    const float colbase = (float)((j * 64) & 127) + (float)(quad * 4);
    float ps = 0.f, pc = 0.f;
    #pragma unroll
    for (int s = 0; s < 4; s++) {
      float p0 = __expf(sf[s][0] - mnew);
      float p1 = __expf(sf[s][1] - mnew);
      float p2 = __expf(sf[s][2] - mnew);
      float p3 = __expf(sf[s][3] - mnew);
      ps += p0 + p1 + p2 + p3;
      const float cb = colbase + (float)(s * 16);
      pc += p0 * cb + p1 * (cb + 1.f) + p2 * (cb + 2.f) + p3 * (cb + 3.f);
      Pk4 pk;
      pk.u[0] = f2h(p0); pk.u[1] = f2h(p1); pk.u[2] = f2h(p2); pk.u[3] = f2h(p3);
      *(uintx2*)&P_lds[wv][ln16 * 76 + s * 16 + quad * 4] = pk.v;  // b64 write
    }
    ps += __shfl_xor(ps, 16); ps += __shfl_xor(ps, 32);
    pc += __shfl_xor(pc, 16); pc += __shfl_xor(pc, 32);
    l_q  = l_q  * alpha + ps;
    aC_q = aC_q * alpha + pc;
    #pragma unroll
    for (int v = 0; v < 8; v++) accO[v] *= alpha;

    // no barrier: P_lds is wave-private; DS ops are in-order per wave.
    half8 pb0 = as_h8(*(const uintx4*)&P_lds[wv][ln16 * 76 + quad * 8]);
    half8 pb1 = as_h8(*(const uintx4*)&P_lds[wv][ln16 * 76 + 32 + quad * 8]);
    #pragma unroll
    for (int vt = 0; vt < 8; vt++) {
      uintx4 ag0 = g_lds[buf][quad * 129 + vt * 16 + ln16];
      uintx4 ag1 = g_lds[buf][(4 + quad) * 129 + vt * 16 + ln16];
      accO[vt] = __builtin_amdgcn_mfma_f32_16x16x32_f16(as_h8(ag0), pb0, accO[vt], 0, 0, 0);
      accO[vt] = __builtin_amdgcn_mfma_f32_16x16x32_f16(as_h8(ag1), pb1, accO[vt], 0, 0, 0);
    }
  }

  // epilogue: per lane one query q=ln16; v contiguous in chunks of 4 -> b64.
  const int q = q0 + wv * 16 + ln16;
  const size_t p = (size_t)side * 32768 + (size_t)split * 16384 + b * HW + q;
  u16* orow = pO + p * RP;
  #pragma unroll
  for (int vt = 0; vt < 8; vt++) {
    Pk4 pk;
    #pragma unroll
    for (int r = 0; r < 4; r++) pk.u[r] = f2h(accO[vt][r]);
    *(uintx2*)(orow + vt * 16 + quad * 4) = pk.v;
  }
  if (quad == 0) {
    floatx4 m4; m4[0] = m_q; m4[1] = l_q; m4[2] = aC_q; m4[3] = 0.f;
    *(floatx4*)(mla + p * 4) = m4;
  }
}

// ---------------------------------------------------------------------------
// Combine split-K partials (both sides): after (bf16) + index (fp32).
// Block 256 = 2 (side,query) pairs x 128 v. pp in [0, 32768).
// ---------------------------------------------------------------------------
__global__ __launch_bounds__(256) void ra_combine(
    const u16* __restrict__ pO, const float* __restrict__ mla,
    u16* __restrict__ afterL, u16* __restrict__ afterR,
    float* __restrict__ idxL, float* __restrict__ idxR)
{
  const int t = threadIdx.x;
  const int pp = blockIdx.x * 2 + (t >> 7);
  const int side = pp >> 14;
  const int p = pp & 16383;
  const int v = t & 127;
  const size_t base = (size_t)side * 32768;
  const floatx4 A  = *(const floatx4*)(mla + (base + p) * 4);
  const floatx4 Bv = *(const floatx4*)(mla + (base + 16384 + p) * 4);
  const float M  = fmaxf(A[0], Bv[0]);
  const float w0 = __expf(A[0] - M), w1 = __expf(Bv[0] - M);
  const float inv = 1.0f / (w0 * A[1] + w1 * Bv[1]);
  const float a0 = h2f(pO[(base + p) * RP + v]);
  const float a1 = h2f(pO[(base + 16384 + p) * RP + v]);
  u16* after = side ? afterR : afterL;
  after[(size_t)p * RP + v] = f2bf((w0 * a0 + w1 * a1) * inv);
  if (v == 0) {
    float* idx = side ? idxR : idxL;
    idx[p] = (float)(p & 127) - (w0 * A[2] + w1 * Bv[2]) * inv;
  }
}

// ---------------------------------------------------------------------------
// Up-projection (both sides): y[b,co,pos] = after[b,pos,:]·up_w[co,:] + up_b
// ---------------------------------------------------------------------------
__global__ __launch_bounds__(256) void ra_up(
    const u16* __restrict__ afterL, const u16* __restrict__ afterR,
    const float* __restrict__ w, const float* __restrict__ bias,
    u16* __restrict__ yL, u16* __restrict__ yR)
{
  __shared__ float x_lds[32][68];   // [r][pos]
  __shared__ float w_lds[32][132];  // [r][co]
  const int tid  = threadIdx.x;
  const int bx   = blockIdx.x;
  const int side = bx >> 9;
  const int sbx  = bx & 511;
  const u16* __restrict__ after = side ? afterR : afterL;
  u16* __restrict__ y = side ? yR : yL;
  const int b    = sbx >> 7;
  const int pos0 = ((sbx >> 1) & 63) * 64;
  const int hc   = sbx & 1;
  const int rt = tid & 15, pt = tid >> 4;

  float acc[4][8];
  #pragma unroll
  for (int i = 0; i < 4; i++)
    #pragma unroll
    for (int j = 0; j < 8; j++) acc[i][j] = 0.f;

  const int apos = tid >> 2, ars = (tid & 3) * 8;
  const int wr_ = tid >> 1, wc_ = (tid & 1) * 16;

  for (int cc = 0; cc < 4; ++cc) {
    {
      const u16* ar = after + (size_t)(b * HW + pos0 + apos) * RP + cc * 32 + ars;
      uintx4 raw = *(const uintx4*)ar;
      #pragma unroll
      for (int k = 0; k < 4; k++) {
        u32 wd = raw[k];
        x_lds[ars + 2 * k][apos]     = bf2f((u16)(wd & 0xffffu));
        x_lds[ars + 2 * k + 1][apos] = bf2f((u16)(wd >> 16));
      }
    }
    {
      const float* wp = w + (size_t)(hc * 128 + wr_) * RP + cc * 32 + wc_;
      #pragma unroll
      for (int jj = 0; jj < 16; jj++) w_lds[wc_ + jj][wr_] = wp[jj];
    }
    __syncthreads();
    #pragma unroll 8
    for (int c = 0; c < 32; c++) {
      floatx4 xv = *(const floatx4*)&x_lds[c][pt * 4];
      floatx4 w0 = *(const floatx4*)&w_lds[c][rt * 8];
      floatx4 w1 = *(const floatx4*)&w_lds[c][rt * 8 + 4];
      #pragma unroll
      for (int i = 0; i < 4; i++) {
        acc[i][0] += xv[i] * w0[0]; acc[i][1] += xv[i] * w0[1];
        acc[i][2] += xv[i] * w0[2]; acc[i][3] += xv[i] * w0[3];
        acc[i][4] += xv[i] * w1[0]; acc[i][5] += xv[i] * w1[1];
        acc[i][6] += xv[i] * w1[2]; acc[i][7] += xv[i] * w1[3];
      }
    }
    __syncthreads();
  }

  #pragma unroll
  for (int j = 0; j < 8; j++) {
    const int co = hc * 128 + rt * 8 + j;
    const float bs = bias[co];
    Pk4 pk;
    #pragma unroll
    for (int i = 0; i < 4; i++) pk.u[i] = f2bf(acc[i][j] + bs);
    *(uintx2*)(y + (size_t)(b * CB + co) * HW + pos0 + pt * 4) = pk.v;
  }
}

// ---------------------------------------------------------------------------
// Per-channel batch stats (both sides) over (B, HW): mean and rstd.
// ---------------------------------------------------------------------------
__global__ __launch_bounds__(256) void ra_stats(
    const u16* __restrict__ yL, const u16* __restrict__ yR,
    float* __restrict__ stL, float* __restrict__ stR)
{
  const int side = blockIdx.x >> 8;
  const int c = blockIdx.x & 255;
  const u16* __restrict__ y = side ? yR : yL;
  float* __restrict__ stats = side ? stR : stL;
  const int tid = threadIdx.x;
  float s = 0.f, sq = 0.f;
  for (int b = 0; b < 4; b++) {
    const uintx4* row = (const uintx4*)(y + (size_t)(b * CB + c) * HW);
    #pragma unroll
    for (int t = 0; t < 2; t++) {
      uintx4 rv = row[tid + t * 256];
      #pragma unroll
      for (int k = 0; k < 4; k++) {
        float a0 = bf2f((u16)(rv[k] & 0xffffu));
        float a1 = bf2f((u16)(rv[k] >> 16));
        s += a0 + a1; sq += a0 * a0 + a1 * a1;
      }
    }
  }
  #pragma unroll
  for (int m = 1; m < 64; m <<= 1) { s += __shfl_xor(s, m); sq += __shfl_xor(sq, m); }
  __shared__ float red[8];
  const int wv = tid >> 6;
  if ((tid & 63) == 0) { red[wv * 2] = s; red[wv * 2 + 1] = sq; }
  __syncthreads();
  if (tid == 0) {
    s  = red[0] + red[2] + red[4] + red[6];
    sq = red[1] + red[3] + red[5] + red[7];
    const float mean = s * (1.f / 16384.f);
    const float var  = sq * (1.f / 16384.f) - mean * mean;
    stats[2 * c]     = mean;
    stats[2 * c + 1] = rsqrtf(var + EPSF);
  }
}

// ---------------------------------------------------------------------------
// out = x + gamma*(y - mean)*rstd + beta  (both sides, float4)
// ---------------------------------------------------------------------------
__global__ __launch_bounds__(256) void ra_fin(
    const float* __restrict__ left, const float* __restrict__ right,
    const u16* __restrict__ yL, const u16* __restrict__ yR,
    const float* __restrict__ stL, const float* __restrict__ stR,
    const float* __restrict__ gamma, const float* __restrict__ beta,
    float* __restrict__ out)
{
  const size_t e = (size_t)blockIdx.x * 256 + threadIdx.x;  // global float4 idx
  const int side = (int)(e >> 20);
  const size_t e4 = e & 1048575;
  const int c = (int)((e4 >> 10) & 255);
  const float* x = side ? right : left;
  const u16* y = side ? yR : yL;
  const float* stats = side ? stR : stL;
  const float mean = stats[2 * c], rstd = stats[2 * c + 1];
  const float ga = gamma[c], be = beta[c];
  floatx4 xv = ((const floatx4*)x)[e4];
  uintx2 yv = ((const uintx2*)y)[e4];
  float f0 = bf2f((u16)(yv[0] & 0xffffu));
  float f1 = bf2f((u16)(yv[0] >> 16));
  float f2 = bf2f((u16)(yv[1] & 0xffffu));
  float f3 = bf2f((u16)(yv[1] >> 16));
  floatx4 o;
  o[0] = xv[0] + ga * ((f0 - mean) * rstd) + be;
  o[1] = xv[1] + ga * ((f1 - mean) * rstd) + be;
  o[2] = xv[2] + ga * ((f2 - mean) * rstd) + be;
  o[3] = xv[3] + ga * ((f3 - mean) * rstd) + be;
  ((floatx4*)out)[(size_t)side * 1048576 + e4] = o;
}

// ---------------------------------------------------------------------------
extern "C" void kernel_launch(void* const* d_in, const int* in_sizes, int n_in,
                              void* d_out, int out_size, void* d_ws, size_t ws_size,
                              hipStream_t stream)
{
  const float* left    = (const float*)d_in[0];
  const float* right   = (const float*)d_in[1];
  const float* pre_l   = (const float*)d_in[2];
  const float* pre_r   = (const float*)d_in[3];
  const float* query_l = (const float*)d_in[4];
  const float* key_l   = (const float*)d_in[5];
  const float* query_r = (const float*)d_in[6];
  const float* key_r   = (const float*)d_in[7];
  const float* theta_w = (const float*)d_in[8];
  const float* theta_b = (const float*)d_in[9];
  const float* phi_w   = (const float*)d_in[10];
  const float* phi_b   = (const float*)d_in[11];
  const float* g_w     = (const float*)d_in[12];
  const float* g_b     = (const float*)d_in[13];
  const float* up_w    = (const float*)d_in[14];
  const float* up_b    = (const float*)d_in[15];
  const float* bn_g    = (const float*)d_in[16];
  const float* bn_b    = (const float*)d_in[17];
  float* out = (float*)d_out;

  char* ws = (char*)d_ws;
  const size_t SZ = (size_t)4 * HW * RP * 2;  // 4 MiB (fp16 [4][4096][128])
  u16* thetaL = (u16*)(ws);
  u16* phiTL  = (u16*)(ws + 1 * SZ);
  u16* gTL    = (u16*)(ws + 2 * SZ);
  u16* thetaR = (u16*)(ws + 3 * SZ);
  u16* phiTR  = (u16*)(ws + 4 * SZ);
  u16* gTR    = (u16*)(ws + 5 * SZ);
  u16* afterL = (u16*)(ws + 6 * SZ);
  u16* afterR = (u16*)(ws + 7 * SZ);
  u16* pO     = (u16*)(ws + 8 * SZ);    // 16 MiB (2 sides x 2 splits), aliased w/ y
  u16* yL     = (u16*)(ws + 8 * SZ);    // 8 MiB (written after pO is consumed)
  u16* yR     = (u16*)(ws + 10 * SZ);   // 8 MiB
  float* stL  = (float*)(ws + 12 * SZ);
  float* stR  = (float*)(ws + 12 * SZ + 2048);
  float* mla  = (float*)(ws + 12 * SZ + 8192);  // 1 MiB (65536 x 4 fp32)

  dim3 blk(256);
  // side L: x_q=left, x_kv=right, query_l, key_r; side R mirrored.
  ProjCfg6 pc;
  pc.c[0] = { left,  theta_w, theta_b, query_l, pre_l,   thetaL, 257, 0 };
  pc.c[1] = { right, phi_w,   phi_b,   key_r,   nullptr, phiTL,  256, 0 };
  pc.c[2] = { right, g_w,     g_b,     nullptr, nullptr, gTL,    256, 1 };
  pc.c[3] = { right, theta_w, theta_b, query_r, pre_r,   thetaR, 257, 0 };
  pc.c[4] = { left,  phi_w,   phi_b,   key_l,   nullptr, phiTR,  256, 0 };
  pc.c[5] = { left,  g_w,     g_b,     nullptr, nullptr, gTR,    256, 1 };
  ra_proj6<<<1536, blk, 0, stream>>>(pc);

  ra_flash<<<1024, blk, 0, stream>>>(thetaL, phiTL, gTL, thetaR, phiTR, gTR, pO, mla);
  ra_combine<<<16384, blk, 0, stream>>>(pO, mla, afterL, afterR,
                                        out + 8388608, out + 8404992);
  ra_up<<<1024, blk, 0, stream>>>(afterL, afterR, up_w, up_b, yL, yR);
  ra_stats<<<512, blk, 0, stream>>>(yL, yR, stL, stR);
  ra_fin<<<8192, blk, 0, stream>>>(left, right, yL, yR, stL, stR, bn_g, bn_b, out);

  (void)in_sizes; (void)n_in; (void)out_size; (void)ws_size;
}